// Round 2
// baseline (472.541 us; speedup 1.0000x reference)
//
#include <hip/hip_runtime.h>
#include <hip/hip_bf16.h>

#define GN 8192
#define GD 128
#define NW_WORDS (GN*(GN/64))   // 1,048,576 adj bitmask words
#define LOG2E 1.44269504088896f
#define JSPLIT 8
#define GEMM_BLKS (GN/16)       // 512

typedef __attribute__((ext_vector_type(8))) short short8;
typedef __attribute__((ext_vector_type(16))) float f32x16;

static __device__ __forceinline__ unsigned short f2bf(float f){
  unsigned u = __float_as_uint(f);
  u = (u + 0x7FFFu + ((u >> 16) & 1u)) >> 16;   // RNE
  return (unsigned short)u;
}
static __device__ __forceinline__ float bf2f(unsigned short s){
  return __uint_as_float(((unsigned)s) << 16);
}
static __device__ __forceinline__ float lrelu(float x){ return fmaxf(x, 0.2f*x); }
static __device__ __forceinline__ float exp2_fast(float x){
#if __has_builtin(__builtin_amdgcn_exp2f)
  return __builtin_amdgcn_exp2f(x);
#else
  return exp2f(x);
#endif
}

// ---------------- prep: coop_norm + cmax-key init -----------------
__global__ __launch_bounds__(256) void k_prep(const float* __restrict__ loss,
    const float* __restrict__ cw, const float* __restrict__ cb,
    float* __restrict__ coopn, unsigned* __restrict__ cmaxk){
  int i = blockIdx.x*256 + threadIdx.x;
  if (i < GN){
    float z = cw[0]*loss[i] + cb[0];
    coopn[i] = 1.0f/(1.0f + expf(-z));
  }
  if (i == 0){ cmaxk[0] = 0u; cmaxk[1] = 0u; }
}

// ---- Wh = X@W ; r=(Wh@a_src+coopn)*LOG2E ; c likewise ; Wpk packed bf16 ----
// Wpk layout: [j>>4][d][j&15]  -> MFMA B-frag loads are 2KB-contiguous per wave.
// PACK=true: blocks >= GEMM_BLKS additionally pack adj -> bitmask (overlap).
template<int K, bool PACK>
__global__ __launch_bounds__(256) void k_gemm(const float* __restrict__ X,
    const float* __restrict__ W, const float* __restrict__ a_src,
    const float* __restrict__ a_dst, const float* __restrict__ coopn,
    unsigned short* __restrict__ Wpk, float* __restrict__ rh,
    float* __restrict__ ch, unsigned* __restrict__ cmaxk,
    const int* __restrict__ adj, unsigned long long* __restrict__ bits){
  __shared__ float Xs[16][68];
  __shared__ float Ws[64][132];
  __shared__ float red_s[16][66];
  __shared__ float red_d[16][66];

  if (PACK && blockIdx.x >= GEMM_BLKS){
    int lane = threadIdx.x & 63;
    int w    = ((blockIdx.x - GEMM_BLKS)*256 + threadIdx.x) >> 6;
    int stride = ((gridDim.x - GEMM_BLKS)*256) >> 6;
    for (; w < NW_WORDS; w += stride){
      int a = adj[(size_t)w*64 + lane];
      unsigned long long m = __ballot(a != 0);
      if (lane == 0) bits[w] = m;
    }
    return;
  }

  const int t = threadIdx.x;
  const int rowbase = blockIdx.x * 16;
  const int cg = t >> 2;      // cols 2cg, 2cg+1
  const int rg = t & 3;       // rows rg*4 .. rg*4+3
  float acc[4][2];
  #pragma unroll
  for (int rr=0;rr<4;++rr){ acc[rr][0]=0.f; acc[rr][1]=0.f; }

  for (int kt = 0; kt < K; kt += 64){
    { // stage X tile [16][64]
      int row = t >> 4, c4 = (t & 15)*4;
      float4 v = *(const float4*)&X[(size_t)(rowbase+row)*K + kt + c4];
      *(float4*)&Xs[row][c4] = v;
    }
    #pragma unroll
    for (int i = 0; i < 8; ++i){ // stage W tile [64][128]
      int f4 = i*256 + t;
      int row = f4 >> 5, c4 = (f4 & 31)*4;
      float4 v = *(const float4*)&W[(size_t)(kt+row)*GD + c4];
      *(float4*)&Ws[row][c4] = v;
    }
    __syncthreads();
    #pragma unroll 4
    for (int k = 0; k < 64; k += 4){
      float4 xa[4];
      #pragma unroll
      for (int rr=0;rr<4;++rr) xa[rr] = *(const float4*)&Xs[rg*4+rr][k];
      #pragma unroll
      for (int kk=0;kk<4;++kk){
        float w0 = Ws[k+kk][cg*2+0];
        float w1 = Ws[k+kk][cg*2+1];
        #pragma unroll
        for (int rr=0;rr<4;++rr){
          float x = (&xa[rr].x)[kk];
          acc[rr][0] = fmaf(x, w0, acc[rr][0]);
          acc[rr][1] = fmaf(x, w1, acc[rr][1]);
        }
      }
    }
    __syncthreads();
  }

  // packed bf16 writes: element (j,d) at ((j>>4)*128 + d)*16 + (j&15)
  #pragma unroll
  for (int cc=0; cc<2; ++cc){
    int col = cg*2+cc;
    ushort4 v;
    v.x = f2bf(acc[0][cc]); v.y = f2bf(acc[1][cc]);
    v.z = f2bf(acc[2][cc]); v.w = f2bf(acc[3][cc]);
    *(ushort4*)&Wpk[((size_t)(rowbase>>4)*128 + col)*16 + rg*4] = v;
  }
  // src/dst partial dot products
  float as0=a_src[cg*2], as1=a_src[cg*2+1], ad0=a_dst[cg*2], ad1=a_dst[cg*2+1];
  #pragma unroll
  for (int rr=0; rr<4; ++rr){
    red_s[rg*4+rr][cg] = acc[rr][0]*as0 + acc[rr][1]*as1;
    red_d[rg*4+rr][cg] = acc[rr][0]*ad0 + acc[rr][1]*ad1;
  }
  __syncthreads();
  if (t < 64){
    int row = t & 15, q = t >> 4;
    float s=0.f, d=0.f;
    #pragma unroll
    for (int j=0;j<16;++j){ s += red_s[row][q*16+j]; d += red_d[row][q*16+j]; }
    s += __shfl_xor(s,16); d += __shfl_xor(d,16);
    s += __shfl_xor(s,32); d += __shfl_xor(d,32);
    if (q == 0){
      int i = rowbase + row;
      float cn = coopn[i];
      rh[i] = (s + cn) * LOG2E;
      float cv = (d + cn) * LOG2E;
      ch[i] = cv;
      unsigned b = __float_as_uint(cv);
      unsigned key = (b & 0x80000000u) ? ~b : (b | 0x80000000u);
      #pragma unroll
      for (int m=1; m<16; m<<=1){
        unsigned o = (unsigned)__shfl_xor((int)key, m);
        key = o > key ? o : key;
      }
      if (row == 0) atomicMax(cmaxk, key);
    }
  }
}

// ---------------- fused mask+softmax-weights+MFMA aggregation -----------------
// grid 512 = 64 rowtiles(128 rows) x 8 j-splits(1024 cols). 4 waves x 32 rows.
__global__ __launch_bounds__(256) void k_agg(const unsigned short* __restrict__ Wpk,
    const float* __restrict__ rh, const float* __restrict__ ch,
    const unsigned* __restrict__ cmaxk, const unsigned long long* __restrict__ bits,
    unsigned short* __restrict__ numpart, float* __restrict__ denpart){
  const int t = threadIdx.x;
  const int lane = t & 63;
  const int wid  = t >> 6;              // 0..3
  const int rowtile = blockIdx.x >> 3;  // 0..63
  const int jp      = blockIdx.x & 7;   // 0..7
  const int half = lane >> 5;
  const int l31  = lane & 31;
  const int row  = rowtile*128 + wid*32 + l31;

  unsigned key = cmaxk[0];
  float cmax = __uint_as_float((key & 0x80000000u) ? (key ^ 0x80000000u) : ~key);
  float rv = rh[row];
  float mh = lrelu(rv + cmax);          // scaled row-max upper bound

  f32x16 acc[4];
  #pragma unroll
  for (int cf=0; cf<4; ++cf){
    #pragma unroll
    for (int r=0;r<16;++r) acc[cf][r] = 0.0f;
  }
  float ds0 = 0.f, ds1 = 0.f;

  for (int jt = 0; jt < 16; ++jt){
    const int jb = jp*1024 + jt*64;
    const unsigned long long word = bits[(size_t)row*(GN/64) + (jb >> 6)];
    const unsigned long long wsh = word >> (half*8);
    #pragma unroll
    for (int s = 0; s < 4; ++s){
      const int j0 = jb + s*16 + half*8;
      const int jblk = (jb >> 4) + s;
      const unsigned byt = ((unsigned)(wsh >> (s*16))) & 0xFFu;
      float4 cA = *(const float4*)&ch[j0];
      float4 cB = *(const float4*)&ch[j0+4];
      float cv[8] = {cA.x,cA.y,cA.z,cA.w,cB.x,cB.y,cB.z,cB.w};
      short8 afrag;
      #pragma unroll
      for (int e=0;e<8;++e){
        float a = lrelu(rv + cv[e]) - mh;
        a = ((byt >> e) & 1u) ? a : -1.0e30f;
        float wv = exp2_fast(a);
        if (e & 1) ds1 += wv; else ds0 += wv;
        afrag[e] = (short)__bfloat16_as_ushort(__float2bfloat16(wv));
      }
      #pragma unroll
      for (int cf=0; cf<4; ++cf){
        const short8 bfrag = *(const short8*)&Wpk[((size_t)jblk*GD + cf*32 + l31)*16 + half*8];
        acc[cf] = __builtin_amdgcn_mfma_f32_32x32x16_bf16(afrag, bfrag, acc[cf], 0, 0, 0);
      }
    }
  }
  float dsum = ds0 + ds1;
  dsum += __shfl_xor(dsum, 32);
  if (lane < 32) denpart[(size_t)jp*GN + row] = dsum;

  const int rbase = rowtile*128 + wid*32 + 4*half;
  #pragma unroll
  for (int cf=0; cf<4; ++cf){
    const int col = cf*32 + l31;
    #pragma unroll
    for (int r=0;r<16;++r){
      const int orow = rbase + (r & 3) + 8*(r >> 2);
      numpart[(size_t)jp*GN*GD + (size_t)orow*GD + col] = f2bf(acc[cf][r]);
    }
  }
}

// ---------------- combine partials, normalize, elu -----------------
__global__ __launch_bounds__(256) void k_combine(const unsigned short* __restrict__ numpart,
    const float* __restrict__ denpart, float* __restrict__ out){
  const int idx = blockIdx.x*256 + threadIdx.x;   // 0..GN*GD-1
  const int i = idx >> 7;
  float s = 0.f, den = 0.f;
  #pragma unroll
  for (int p=0;p<JSPLIT;++p) s += bf2f(numpart[(size_t)p*GN*GD + idx]);
  #pragma unroll
  for (int p=0;p<JSPLIT;++p) den += denpart[(size_t)p*GN + i];
  float v = s/den;
  out[idx] = v > 0.f ? v : expm1f(v);
}

extern "C" void kernel_launch(void* const* d_in, const int* in_sizes, int n_in,
                              void* d_out, int out_size, void* d_ws, size_t ws_size,
                              hipStream_t stream){
  (void)in_sizes; (void)n_in; (void)out_size; (void)ws_size;
  const float* V    = (const float*)d_in[0];
  const int*   adj  = (const int*)d_in[1];
  const float* loss = (const float*)d_in[2];
  const float* W1   = (const float*)d_in[3];
  const float* as1  = (const float*)d_in[4];
  const float* ad1  = (const float*)d_in[5];
  const float* W2   = (const float*)d_in[6];
  const float* as2  = (const float*)d_in[7];
  const float* ad2  = (const float*)d_in[8];
  const float* cw   = (const float*)d_in[9];
  const float* cb   = (const float*)d_in[10];
  float* out = (float*)d_out;

  char* p = (char*)d_ws;
  auto take = [&](size_t sz) -> char* {
    char* r = p; p += (sz + 255) & ~(size_t)255; return r;
  };
  unsigned long long* bits = (unsigned long long*)take((size_t)NW_WORDS*8); // 8 MB
  float* coopn = (float*)take(GN*4);
  float* r1 = (float*)take(GN*4);
  float* c1 = (float*)take(GN*4);
  float* r2 = (float*)take(GN*4);
  float* c2 = (float*)take(GN*4);
  unsigned* cmaxk = (unsigned*)take(256);
  unsigned short* Wpk1 = (unsigned short*)take((size_t)GN*GD*2);   // 2 MB
  unsigned short* Wpk2 = (unsigned short*)take((size_t)GN*GD*2);   // 2 MB
  float* H1 = (float*)take((size_t)GN*GD*4);                       // 4 MB
  unsigned short* numpart = (unsigned short*)take((size_t)JSPLIT*GN*GD*2); // 16.8 MB
  float* denpart = (float*)take((size_t)JSPLIT*GN*4);              // 0.26 MB

  k_prep<<<GN/256, 256, 0, stream>>>(loss, cw, cb, coopn, cmaxk);

  // layer-1 gemm with adj packing fused in as extra blocks (overlaps HBM & VALU)
  k_gemm<256, true><<<GEMM_BLKS + 4096, 256, 0, stream>>>(
      V, W1, as1, ad1, coopn, Wpk1, r1, c1, cmaxk+0, adj, bits);
  k_agg<<<512, 256, 0, stream>>>(Wpk1, r1, c1, cmaxk+0, bits, numpart, denpart);
  k_combine<<<GN*GD/256, 256, 0, stream>>>(numpart, denpart, H1);

  k_gemm<128, false><<<GEMM_BLKS, 256, 0, stream>>>(
      H1, W2, as2, ad2, coopn, Wpk2, r2, c2, cmaxk+1, nullptr, nullptr);
  k_agg<<<512, 256, 0, stream>>>(Wpk2, r2, c2, cmaxk+1, bits, numpart, denpart);
  k_combine<<<GN*GD/256, 256, 0, stream>>>(numpart, denpart, out);
}

// Round 3
// 271.634 us; speedup vs baseline: 1.7396x; 1.7396x over previous
//
#include <hip/hip_runtime.h>
#include <hip/hip_bf16.h>

#define GN 8192
#define GD 128
#define NW_WORDS (GN*(GN/64))   // 1,048,576 adj bitmask words
#define LOG2E 1.44269504088896f
#define JSPLIT 8

typedef __attribute__((ext_vector_type(8))) short short8;
typedef __attribute__((ext_vector_type(16))) float f32x16;

static __device__ __forceinline__ unsigned short f2bf(float f){
  unsigned u = __float_as_uint(f);
  u = (u + 0x7FFFu + ((u >> 16) & 1u)) >> 16;   // RNE
  return (unsigned short)u;
}
static __device__ __forceinline__ float bf2f(unsigned short s){
  return __uint_as_float(((unsigned)s) << 16);
}
static __device__ __forceinline__ float lrelu(float x){ return fmaxf(x, 0.2f*x); }
static __device__ __forceinline__ float exp2_fast(float x){
#if __has_builtin(__builtin_amdgcn_exp2f)
  return __builtin_amdgcn_exp2f(x);
#else
  return exp2f(x);
#endif
}

// ---------------- prep: coop_norm + cmax-key init -----------------
__global__ __launch_bounds__(256) void k_prep(const float* __restrict__ loss,
    const float* __restrict__ cw, const float* __restrict__ cb,
    float* __restrict__ coopn, unsigned* __restrict__ cmaxk){
  int i = blockIdx.x*256 + threadIdx.x;
  if (i < GN){
    float z = cw[0]*loss[i] + cb[0];
    coopn[i] = 1.0f/(1.0f + expf(-z));
  }
  if (i == 0){ cmaxk[0] = 0u; cmaxk[1] = 0u; }
}

// ---------------- pack adj -> transposed bitmask bits_t[word][row] ------------
// 4 words per wave-iteration: 4 independent 256B loads in flight (ILP), then
// 4 ballots + one 4x8B scalar store burst from lane 0. Tiny kernel, full occ.
__global__ __launch_bounds__(256) void k_pack(const int* __restrict__ adj,
    unsigned long long* __restrict__ bits_t){
  const int lane = threadIdx.x & 63;
  const int wq = (blockIdx.x*256 + threadIdx.x) >> 6;   // global wave id
  const int nw = (gridDim.x*256) >> 6;
  for (int g = wq; g < NW_WORDS/4; g += nw){
    const size_t base = (size_t)g*256;   // 4 words x 64 lanes
    int a0 = adj[base + lane];
    int a1 = adj[base + 64 + lane];
    int a2 = adj[base + 128 + lane];
    int a3 = adj[base + 192 + lane];
    unsigned long long m0 = __ballot(a0 != 0);
    unsigned long long m1 = __ballot(a1 != 0);
    unsigned long long m2 = __ballot(a2 != 0);
    unsigned long long m3 = __ballot(a3 != 0);
    if (lane == 0){
      const int row = g >> 5;            // (g*4)/128
      const int w0  = (g & 31)*4;        // word index within row
      bits_t[(size_t)(w0+0)*GN + row] = m0;
      bits_t[(size_t)(w0+1)*GN + row] = m1;
      bits_t[(size_t)(w0+2)*GN + row] = m2;
      bits_t[(size_t)(w0+3)*GN + row] = m3;
    }
  }
}

// ---- Wh = X@W ; r=(Wh@a_src+coopn)*LOG2E ; c likewise ; Wpk packed bf16 ----
// Wpk layout: [j>>4][d][j&15]  -> MFMA B-frag loads are 2KB-contiguous per wave.
template<int K>
__global__ __launch_bounds__(256) void k_gemm(const float* __restrict__ X,
    const float* __restrict__ W, const float* __restrict__ a_src,
    const float* __restrict__ a_dst, const float* __restrict__ coopn,
    unsigned short* __restrict__ Wpk, float* __restrict__ rh,
    float* __restrict__ ch, unsigned* __restrict__ cmaxk){
  __shared__ float Xs[16][68];
  __shared__ float Ws[64][132];
  __shared__ float red_s[16][66];
  __shared__ float red_d[16][66];
  const int t = threadIdx.x;
  const int rowbase = blockIdx.x * 16;
  const int cg = t >> 2;      // cols 2cg, 2cg+1
  const int rg = t & 3;       // rows rg*4 .. rg*4+3
  float acc[4][2];
  #pragma unroll
  for (int rr=0;rr<4;++rr){ acc[rr][0]=0.f; acc[rr][1]=0.f; }

  for (int kt = 0; kt < K; kt += 64){
    { // stage X tile [16][64]
      int row = t >> 4, c4 = (t & 15)*4;
      float4 v = *(const float4*)&X[(size_t)(rowbase+row)*K + kt + c4];
      *(float4*)&Xs[row][c4] = v;
    }
    #pragma unroll
    for (int i = 0; i < 8; ++i){ // stage W tile [64][128]
      int f4 = i*256 + t;
      int row = f4 >> 5, c4 = (f4 & 31)*4;
      float4 v = *(const float4*)&W[(size_t)(kt+row)*GD + c4];
      *(float4*)&Ws[row][c4] = v;
    }
    __syncthreads();
    #pragma unroll 4
    for (int k = 0; k < 64; k += 4){
      float4 xa[4];
      #pragma unroll
      for (int rr=0;rr<4;++rr) xa[rr] = *(const float4*)&Xs[rg*4+rr][k];
      #pragma unroll
      for (int kk=0;kk<4;++kk){
        float w0 = Ws[k+kk][cg*2+0];
        float w1 = Ws[k+kk][cg*2+1];
        #pragma unroll
        for (int rr=0;rr<4;++rr){
          float x = (&xa[rr].x)[kk];
          acc[rr][0] = fmaf(x, w0, acc[rr][0]);
          acc[rr][1] = fmaf(x, w1, acc[rr][1]);
        }
      }
    }
    __syncthreads();
  }

  // packed bf16 writes: element (j,d) at ((j>>4)*128 + d)*16 + (j&15)
  #pragma unroll
  for (int cc=0; cc<2; ++cc){
    int col = cg*2+cc;
    ushort4 v;
    v.x = f2bf(acc[0][cc]); v.y = f2bf(acc[1][cc]);
    v.z = f2bf(acc[2][cc]); v.w = f2bf(acc[3][cc]);
    *(ushort4*)&Wpk[((size_t)(rowbase>>4)*128 + col)*16 + rg*4] = v;
  }
  // src/dst partial dot products
  float as0=a_src[cg*2], as1=a_src[cg*2+1], ad0=a_dst[cg*2], ad1=a_dst[cg*2+1];
  #pragma unroll
  for (int rr=0; rr<4; ++rr){
    red_s[rg*4+rr][cg] = acc[rr][0]*as0 + acc[rr][1]*as1;
    red_d[rg*4+rr][cg] = acc[rr][0]*ad0 + acc[rr][1]*ad1;
  }
  __syncthreads();
  if (t < 64){
    int row = t & 15, q = t >> 4;
    float s=0.f, d=0.f;
    #pragma unroll
    for (int j=0;j<16;++j){ s += red_s[row][q*16+j]; d += red_d[row][q*16+j]; }
    s += __shfl_xor(s,16); d += __shfl_xor(d,16);
    s += __shfl_xor(s,32); d += __shfl_xor(d,32);
    if (q == 0){
      int i = rowbase + row;
      float cn = coopn[i];
      rh[i] = (s + cn) * LOG2E;
      float cv = (d + cn) * LOG2E;
      ch[i] = cv;
      unsigned b = __float_as_uint(cv);
      unsigned key = (b & 0x80000000u) ? ~b : (b | 0x80000000u);
      #pragma unroll
      for (int m=1; m<16; m<<=1){
        unsigned o = (unsigned)__shfl_xor((int)key, m);
        key = o > key ? o : key;
      }
      if (row == 0) atomicMax(cmaxk, key);
    }
  }
}

// ---------------- fused mask+softmax-weights+MFMA aggregation -----------------
// grid 512 = 64 rowtiles(128 rows) x 8 j-splits(1024 cols). 4 waves x 32 rows.
__global__ __launch_bounds__(256) void k_agg(const unsigned short* __restrict__ Wpk,
    const float* __restrict__ rh, const float* __restrict__ ch,
    const unsigned* __restrict__ cmaxk, const unsigned long long* __restrict__ bits_t,
    unsigned short* __restrict__ numpart, float* __restrict__ denpart){
  const int t = threadIdx.x;
  const int lane = t & 63;
  const int wid  = t >> 6;              // 0..3
  const int rowtile = blockIdx.x >> 3;  // 0..63
  const int jp      = blockIdx.x & 7;   // 0..7
  const int half = lane >> 5;
  const int l31  = lane & 31;
  const int row  = rowtile*128 + wid*32 + l31;

  unsigned key = cmaxk[0];
  float cmax = __uint_as_float((key & 0x80000000u) ? (key ^ 0x80000000u) : ~key);
  float rv = rh[row];
  float mh = lrelu(rv + cmax);          // scaled row-max upper bound

  f32x16 acc[4];
  #pragma unroll
  for (int cf=0; cf<4; ++cf){
    #pragma unroll
    for (int r=0;r<16;++r) acc[cf][r] = 0.0f;
  }
  float ds0 = 0.f, ds1 = 0.f;

  for (int jt = 0; jt < 16; ++jt){
    const int jb = jp*1024 + jt*64;
    // transposed bitmask: 32 consecutive rows -> 256B contiguous wave read
    const unsigned long long word = bits_t[(size_t)(jb >> 6)*GN + row];
    const unsigned long long wsh = word >> (half*8);
    #pragma unroll
    for (int s = 0; s < 4; ++s){
      const int j0 = jb + s*16 + half*8;
      const int jblk = (jb >> 4) + s;
      const unsigned byt = ((unsigned)(wsh >> (s*16))) & 0xFFu;
      float4 cA = *(const float4*)&ch[j0];
      float4 cB = *(const float4*)&ch[j0+4];
      float cv[8] = {cA.x,cA.y,cA.z,cA.w,cB.x,cB.y,cB.z,cB.w};
      short8 afrag;
      #pragma unroll
      for (int e=0;e<8;++e){
        float a = lrelu(rv + cv[e]) - mh;
        a = ((byt >> e) & 1u) ? a : -1.0e30f;
        float wv = exp2_fast(a);
        if (e & 1) ds1 += wv; else ds0 += wv;
        afrag[e] = (short)__bfloat16_as_ushort(__float2bfloat16(wv));
      }
      #pragma unroll
      for (int cf=0; cf<4; ++cf){
        const short8 bfrag = *(const short8*)&Wpk[((size_t)jblk*GD + cf*32 + l31)*16 + half*8];
        acc[cf] = __builtin_amdgcn_mfma_f32_32x32x16_bf16(afrag, bfrag, acc[cf], 0, 0, 0);
      }
    }
  }
  float dsum = ds0 + ds1;
  dsum += __shfl_xor(dsum, 32);
  if (lane < 32) denpart[(size_t)jp*GN + row] = dsum;

  const int rbase = rowtile*128 + wid*32 + 4*half;
  #pragma unroll
  for (int cf=0; cf<4; ++cf){
    const int col = cf*32 + l31;
    #pragma unroll
    for (int r=0;r<16;++r){
      const int orow = rbase + (r & 3) + 8*(r >> 2);
      numpart[(size_t)jp*GN*GD + (size_t)orow*GD + col] = f2bf(acc[cf][r]);
    }
  }
}

// ---------------- combine partials, normalize, elu -----------------
__global__ __launch_bounds__(256) void k_combine(const unsigned short* __restrict__ numpart,
    const float* __restrict__ denpart, float* __restrict__ out){
  const int idx = blockIdx.x*256 + threadIdx.x;   // 0..GN*GD-1
  const int i = idx >> 7;
  float s = 0.f, den = 0.f;
  #pragma unroll
  for (int p=0;p<JSPLIT;++p) s += bf2f(numpart[(size_t)p*GN*GD + idx]);
  #pragma unroll
  for (int p=0;p<JSPLIT;++p) den += denpart[(size_t)p*GN + i];
  float v = s/den;
  out[idx] = v > 0.f ? v : expm1f(v);
}

extern "C" void kernel_launch(void* const* d_in, const int* in_sizes, int n_in,
                              void* d_out, int out_size, void* d_ws, size_t ws_size,
                              hipStream_t stream){
  (void)in_sizes; (void)n_in; (void)out_size; (void)ws_size;
  const float* V    = (const float*)d_in[0];
  const int*   adj  = (const int*)d_in[1];
  const float* loss = (const float*)d_in[2];
  const float* W1   = (const float*)d_in[3];
  const float* as1  = (const float*)d_in[4];
  const float* ad1  = (const float*)d_in[5];
  const float* W2   = (const float*)d_in[6];
  const float* as2  = (const float*)d_in[7];
  const float* ad2  = (const float*)d_in[8];
  const float* cw   = (const float*)d_in[9];
  const float* cb   = (const float*)d_in[10];
  float* out = (float*)d_out;

  char* p = (char*)d_ws;
  auto take = [&](size_t sz) -> char* {
    char* r = p; p += (sz + 255) & ~(size_t)255; return r;
  };
  unsigned long long* bits = (unsigned long long*)take((size_t)NW_WORDS*8); // 8 MB
  float* coopn = (float*)take(GN*4);
  float* r1 = (float*)take(GN*4);
  float* c1 = (float*)take(GN*4);
  float* r2 = (float*)take(GN*4);
  float* c2 = (float*)take(GN*4);
  unsigned* cmaxk = (unsigned*)take(256);
  unsigned short* Wpk1 = (unsigned short*)take((size_t)GN*GD*2);   // 2 MB
  unsigned short* Wpk2 = (unsigned short*)take((size_t)GN*GD*2);   // 2 MB
  float* H1 = (float*)take((size_t)GN*GD*4);                       // 4 MB
  unsigned short* numpart = (unsigned short*)take((size_t)JSPLIT*GN*GD*2); // 16.8 MB
  float* denpart = (float*)take((size_t)JSPLIT*GN*4);              // 0.26 MB

  k_prep<<<GN/256, 256, 0, stream>>>(loss, cw, cb, coopn, cmaxk);
  k_pack<<<4096, 256, 0, stream>>>(adj, bits);

  k_gemm<256><<<GN/16, 256, 0, stream>>>(V,  W1, as1, ad1, coopn, Wpk1, r1, c1, cmaxk+0);
  k_agg<<<512, 256, 0, stream>>>(Wpk1, r1, c1, cmaxk+0, bits, numpart, denpart);
  k_combine<<<GN*GD/256, 256, 0, stream>>>(numpart, denpart, H1);

  k_gemm<128><<<GN/16, 256, 0, stream>>>(H1, W2, as2, ad2, coopn, Wpk2, r2, c2, cmaxk+1);
  k_agg<<<512, 256, 0, stream>>>(Wpk2, r2, c2, cmaxk+1, bits, numpart, denpart);
  k_combine<<<GN*GD/256, 256, 0, stream>>>(numpart, denpart, out);
}

// Round 4
// 237.458 us; speedup vs baseline: 1.9900x; 1.1439x over previous
//
#include <hip/hip_runtime.h>
#include <hip/hip_bf16.h>

#define GN 8192
#define GD 128
#define NWR (GN/64)             // 128 bitmask words per row
#define LOG2E 1.44269504088896f
#define JSPLIT 8

typedef __attribute__((ext_vector_type(8))) short short8;
typedef __attribute__((ext_vector_type(16))) float f32x16;

static __device__ __forceinline__ unsigned short f2bf(float f){
  unsigned u = __float_as_uint(f);
  u = (u + 0x7FFFu + ((u >> 16) & 1u)) >> 16;   // RNE
  return (unsigned short)u;
}
static __device__ __forceinline__ float bf2f(unsigned short s){
  return __uint_as_float(((unsigned)s) << 16);
}
static __device__ __forceinline__ float lrelu(float x){ return fmaxf(x, 0.2f*x); }
static __device__ __forceinline__ float exp2_fast(float x){
#if __has_builtin(__builtin_amdgcn_exp2f)
  return __builtin_amdgcn_exp2f(x);
#else
  return exp2f(x);
#endif
}

// ---------------- prep: coop_norm + cmax-key init -----------------
__global__ __launch_bounds__(256) void k_prep(const float* __restrict__ loss,
    const float* __restrict__ cw, const float* __restrict__ cb,
    float* __restrict__ coopn, unsigned* __restrict__ cmaxk){
  int i = blockIdx.x*256 + threadIdx.x;
  if (i < GN){
    float z = cw[0]*loss[i] + cb[0];
    coopn[i] = 1.0f/(1.0f + expf(-z));
  }
  if (i == 0){ cmaxk[0] = 0u; cmaxk[1] = 0u; }
}

// ---- Wh = X@W ; r=(Wh@a_src+coopn)*LOG2E ; c likewise ; Wpk packed bf16 ----
// Wpk layout: [j>>4][d][j&15]  -> MFMA B-frag loads are 2KB-contiguous per wave.
template<int K>
__global__ __launch_bounds__(256) void k_gemm(const float* __restrict__ X,
    const float* __restrict__ W, const float* __restrict__ a_src,
    const float* __restrict__ a_dst, const float* __restrict__ coopn,
    unsigned short* __restrict__ Wpk, float* __restrict__ rh,
    float* __restrict__ ch, unsigned* __restrict__ cmaxk){
  __shared__ float Xs[16][68];
  __shared__ float Ws[64][132];
  __shared__ float red_s[16][66];
  __shared__ float red_d[16][66];
  const int t = threadIdx.x;
  const int rowbase = blockIdx.x * 16;
  const int cg = t >> 2;      // cols 2cg, 2cg+1
  const int rg = t & 3;       // rows rg*4 .. rg*4+3
  float acc[4][2];
  #pragma unroll
  for (int rr=0;rr<4;++rr){ acc[rr][0]=0.f; acc[rr][1]=0.f; }

  for (int kt = 0; kt < K; kt += 64){
    { // stage X tile [16][64]
      int row = t >> 4, c4 = (t & 15)*4;
      float4 v = *(const float4*)&X[(size_t)(rowbase+row)*K + kt + c4];
      *(float4*)&Xs[row][c4] = v;
    }
    #pragma unroll
    for (int i = 0; i < 8; ++i){ // stage W tile [64][128]
      int f4 = i*256 + t;
      int row = f4 >> 5, c4 = (f4 & 31)*4;
      float4 v = *(const float4*)&W[(size_t)(kt+row)*GD + c4];
      *(float4*)&Ws[row][c4] = v;
    }
    __syncthreads();
    #pragma unroll 4
    for (int k = 0; k < 64; k += 4){
      float4 xa[4];
      #pragma unroll
      for (int rr=0;rr<4;++rr) xa[rr] = *(const float4*)&Xs[rg*4+rr][k];
      #pragma unroll
      for (int kk=0;kk<4;++kk){
        float w0 = Ws[k+kk][cg*2+0];
        float w1 = Ws[k+kk][cg*2+1];
        #pragma unroll
        for (int rr=0;rr<4;++rr){
          float x = (&xa[rr].x)[kk];
          acc[rr][0] = fmaf(x, w0, acc[rr][0]);
          acc[rr][1] = fmaf(x, w1, acc[rr][1]);
        }
      }
    }
    __syncthreads();
  }

  // packed bf16 writes: element (j,d) at ((j>>4)*128 + d)*16 + (j&15)
  #pragma unroll
  for (int cc=0; cc<2; ++cc){
    int col = cg*2+cc;
    ushort4 v;
    v.x = f2bf(acc[0][cc]); v.y = f2bf(acc[1][cc]);
    v.z = f2bf(acc[2][cc]); v.w = f2bf(acc[3][cc]);
    *(ushort4*)&Wpk[((size_t)(rowbase>>4)*128 + col)*16 + rg*4] = v;
  }
  // src/dst partial dot products
  float as0=a_src[cg*2], as1=a_src[cg*2+1], ad0=a_dst[cg*2], ad1=a_dst[cg*2+1];
  #pragma unroll
  for (int rr=0; rr<4; ++rr){
    red_s[rg*4+rr][cg] = acc[rr][0]*as0 + acc[rr][1]*as1;
    red_d[rg*4+rr][cg] = acc[rr][0]*ad0 + acc[rr][1]*ad1;
  }
  __syncthreads();
  if (t < 64){
    int row = t & 15, q = t >> 4;
    float s=0.f, d=0.f;
    #pragma unroll
    for (int j=0;j<16;++j){ s += red_s[row][q*16+j]; d += red_d[row][q*16+j]; }
    s += __shfl_xor(s,16); d += __shfl_xor(d,16);
    s += __shfl_xor(s,32); d += __shfl_xor(d,32);
    if (q == 0){
      int i = rowbase + row;
      float cn = coopn[i];
      rh[i] = (s + cn) * LOG2E;
      float cv = (d + cn) * LOG2E;
      ch[i] = cv;
      unsigned b = __float_as_uint(cv);
      unsigned key = (b & 0x80000000u) ? ~b : (b | 0x80000000u);
      #pragma unroll
      for (int m=1; m<16; m<<=1){
        unsigned o = (unsigned)__shfl_xor((int)key, m);
        key = o > key ? o : key;
      }
      if (row == 0) atomicMax(cmaxk, key);
    }
  }
}

// ---------------- fused mask+softmax-weights+MFMA aggregation -----------------
// grid 512 = 64 rowtiles(128 rows) x 8 j-splits(1024 cols). 4 waves x 32 rows.
// READ_ADJ=true (layer 1): mask from raw adj ints (coalesced 2x int4 per lane),
//   and emit row-major bitmask bits[row][w] as a side product for layer 2.
// READ_ADJ=false (layer 2): mask from bits[row][w] (one 128B line per row&jp).
template<bool READ_ADJ>
__global__ __launch_bounds__(256) void k_agg(const unsigned short* __restrict__ Wpk,
    const float* __restrict__ rh, const float* __restrict__ ch,
    const unsigned* __restrict__ cmaxk, const int* __restrict__ adj,
    unsigned long long* __restrict__ bits,
    unsigned short* __restrict__ numpart, float* __restrict__ denpart){
  const int t = threadIdx.x;
  const int lane = t & 63;
  const int wid  = t >> 6;              // 0..3
  const int rowtile = blockIdx.x >> 3;  // 0..63
  const int jp      = blockIdx.x & 7;   // 0..7
  const int half = lane >> 5;
  const int l31  = lane & 31;
  const int row  = rowtile*128 + wid*32 + l31;

  unsigned key = cmaxk[0];
  float cmax = __uint_as_float((key & 0x80000000u) ? (key ^ 0x80000000u) : ~key);
  float rv = rh[row];
  float mh = lrelu(rv + cmax);          // scaled row-max upper bound

  f32x16 acc[4];
  #pragma unroll
  for (int cf=0; cf<4; ++cf){
    #pragma unroll
    for (int r=0;r<16;++r) acc[cf][r] = 0.0f;
  }
  float ds0 = 0.f, ds1 = 0.f;

  for (int jt = 0; jt < 16; ++jt){
    const int jb = jp*1024 + jt*64;
    unsigned long long word = 0, pw = 0;
    if (!READ_ADJ) word = bits[(size_t)row*NWR + (jb >> 6)];
    const unsigned long long wsh = word >> (half*8);
    #pragma unroll
    for (int s = 0; s < 4; ++s){
      const int j0 = jb + s*16 + half*8;
      const int jblk = (jb >> 4) + s;
      unsigned byt;
      if (READ_ADJ){
        const int4 a0 = *(const int4*)&adj[(size_t)row*GN + j0];
        const int4 a1 = *(const int4*)&adj[(size_t)row*GN + j0 + 4];
        byt  = (a0.x!=0) | ((a0.y!=0)<<1) | ((a0.z!=0)<<2) | ((a0.w!=0)<<3)
             | ((a1.x!=0)<<4) | ((a1.y!=0)<<5) | ((a1.z!=0)<<6) | ((a1.w!=0)<<7);
        pw |= (unsigned long long)byt << (8*(2*s + half));
      } else {
        byt = ((unsigned)(wsh >> (s*16))) & 0xFFu;
      }
      float4 cA = *(const float4*)&ch[j0];
      float4 cB = *(const float4*)&ch[j0+4];
      float cv[8] = {cA.x,cA.y,cA.z,cA.w,cB.x,cB.y,cB.z,cB.w};
      short8 afrag;
      #pragma unroll
      for (int e=0;e<8;++e){
        float a = lrelu(rv + cv[e]) - mh;
        a = ((byt >> e) & 1u) ? a : -1.0e30f;
        float wv = exp2_fast(a);
        if (e & 1) ds1 += wv; else ds0 += wv;
        afrag[e] = (short)__bfloat16_as_ushort(__float2bfloat16(wv));
      }
      #pragma unroll
      for (int cf=0; cf<4; ++cf){
        const short8 bfrag = *(const short8*)&Wpk[((size_t)jblk*GD + cf*32 + l31)*16 + half*8];
        acc[cf] = __builtin_amdgcn_mfma_f32_32x32x16_bf16(afrag, bfrag, acc[cf], 0, 0, 0);
      }
    }
    if (READ_ADJ){
      unsigned long long ow = __shfl_xor(pw, 32);
      if (half == 0) bits[(size_t)row*NWR + (jb >> 6)] = pw | ow;
    }
  }
  float dsum = ds0 + ds1;
  dsum += __shfl_xor(dsum, 32);
  if (lane < 32) denpart[(size_t)jp*GN + row] = dsum;

  const int rbase = rowtile*128 + wid*32 + 4*half;
  #pragma unroll
  for (int cf=0; cf<4; ++cf){
    const int col = cf*32 + l31;
    #pragma unroll
    for (int r=0;r<16;++r){
      const int orow = rbase + (r & 3) + 8*(r >> 2);
      numpart[(size_t)jp*GN*GD + (size_t)orow*GD + col] = f2bf(acc[cf][r]);
    }
  }
}

// ---------------- combine partials, normalize, elu -----------------
__global__ __launch_bounds__(256) void k_combine(const unsigned short* __restrict__ numpart,
    const float* __restrict__ denpart, float* __restrict__ out){
  const int idx = blockIdx.x*256 + threadIdx.x;   // 0..GN*GD-1
  const int i = idx >> 7;
  float s = 0.f, den = 0.f;
  #pragma unroll
  for (int p=0;p<JSPLIT;++p) s += bf2f(numpart[(size_t)p*GN*GD + idx]);
  #pragma unroll
  for (int p=0;p<JSPLIT;++p) den += denpart[(size_t)p*GN + i];
  float v = s/den;
  out[idx] = v > 0.f ? v : expm1f(v);
}

extern "C" void kernel_launch(void* const* d_in, const int* in_sizes, int n_in,
                              void* d_out, int out_size, void* d_ws, size_t ws_size,
                              hipStream_t stream){
  (void)in_sizes; (void)n_in; (void)out_size; (void)ws_size;
  const float* V    = (const float*)d_in[0];
  const int*   adj  = (const int*)d_in[1];
  const float* loss = (const float*)d_in[2];
  const float* W1   = (const float*)d_in[3];
  const float* as1  = (const float*)d_in[4];
  const float* ad1  = (const float*)d_in[5];
  const float* W2   = (const float*)d_in[6];
  const float* as2  = (const float*)d_in[7];
  const float* ad2  = (const float*)d_in[8];
  const float* cw   = (const float*)d_in[9];
  const float* cb   = (const float*)d_in[10];
  float* out = (float*)d_out;

  char* p = (char*)d_ws;
  auto take = [&](size_t sz) -> char* {
    char* r = p; p += (sz + 255) & ~(size_t)255; return r;
  };
  unsigned long long* bits = (unsigned long long*)take((size_t)GN*NWR*8); // 8 MB
  float* coopn = (float*)take(GN*4);
  float* r1 = (float*)take(GN*4);
  float* c1 = (float*)take(GN*4);
  float* r2 = (float*)take(GN*4);
  float* c2 = (float*)take(GN*4);
  unsigned* cmaxk = (unsigned*)take(256);
  unsigned short* Wpk1 = (unsigned short*)take((size_t)GN*GD*2);   // 2 MB
  unsigned short* Wpk2 = (unsigned short*)take((size_t)GN*GD*2);   // 2 MB
  float* H1 = (float*)take((size_t)GN*GD*4);                       // 4 MB
  unsigned short* numpart = (unsigned short*)take((size_t)JSPLIT*GN*GD*2); // 16.8 MB
  float* denpart = (float*)take((size_t)JSPLIT*GN*4);              // 0.26 MB

  k_prep<<<GN/256, 256, 0, stream>>>(loss, cw, cb, coopn, cmaxk);

  k_gemm<256><<<GN/16, 256, 0, stream>>>(V,  W1, as1, ad1, coopn, Wpk1, r1, c1, cmaxk+0);
  k_agg<true><<<512, 256, 0, stream>>>(Wpk1, r1, c1, cmaxk+0, adj, bits, numpart, denpart);
  k_combine<<<GN*GD/256, 256, 0, stream>>>(numpart, denpart, H1);

  k_gemm<128><<<GN/16, 256, 0, stream>>>(H1, W2, as2, ad2, coopn, Wpk2, r2, c2, cmaxk+1);
  k_agg<false><<<512, 256, 0, stream>>>(Wpk2, r2, c2, cmaxk+1, nullptr, bits, numpart, denpart);
  k_combine<<<GN*GD/256, 256, 0, stream>>>(numpart, denpart, out);
}